// Round 2
// baseline (190.792 us; speedup 1.0000x reference)
//
#include <hip/hip_runtime.h>

#define FM_NNZ   819200
#define FM_BATCH 16384
#define FM_K     128
#define UNR      16

__global__ __launch_bounds__(128) void fm_fwd_kernel(
    const float* __restrict__ vals,
    const int*   __restrict__ row_idx,
    const int*   __restrict__ col_idx,
    const float* __restrict__ w0,
    const float* __restrict__ w,
    const float* __restrict__ v,
    float*       __restrict__ out)
{
    const int row = blockIdx.x;
    const int k   = threadIdx.x;          // latent dim, 0..127

    // --- binary search row segment [start, end) in sorted row_idx ---
    int lo = 0, hi = FM_NNZ;
    while (lo < hi) {
        int mid = (lo + hi) >> 1;
        if (row_idx[mid] < row) lo = mid + 1; else hi = mid;
    }
    const int start = lo;
    hi = FM_NNZ;
    while (lo < hi) {
        int mid = (lo + hi) >> 1;
        if (row_idx[mid] < row + 1) lo = mid + 1; else hi = mid;
    }
    const int end = lo;

    float xv = 0.0f;   // sum_i val_i * v[col_i, k]
    float sq = 0.0f;   // sum_i val_i * v[col_i, k]^2

    // --- main loop: 16 nnz batched per iteration, 3 phases so all 16
    //     gathers are independent and in flight simultaneously ---
    for (int base = start; base < end; base += UNR) {
        int   cc[UNR];
        float va[UNR];
        float vv[UNR];
        #pragma unroll
        for (int j = 0; j < UNR; ++j) {
            const int idx = base + j;
            const bool ok = idx < end;
            cc[j] = ok ? col_idx[idx] : 0;   // broadcast loads (same addr all lanes)
            va[j] = ok ? vals[idx]    : 0.0f;
        }
        #pragma unroll
        for (int j = 0; j < UNR; ++j) {
            vv[j] = v[(size_t)cc[j] * FM_K + k];   // 16 independent 512B gathers
        }
        #pragma unroll
        for (int j = 0; j < UNR; ++j) {
            const float t = va[j] * vv[j];
            xv += t;
            sq = fmaf(t, vv[j], sq);
        }
    }

    // --- linear term: strided over threads ---
    float lin = 0.0f;
    for (int i = start + k; i < end; i += FM_K) {
        lin = fmaf(vals[i], w[col_idx[i]], lin);
    }

    // --- reduce (xv^2 - sq) and lin across 128 threads ---
    float local = fmaf(xv, xv, -sq);
    #pragma unroll
    for (int off = 32; off > 0; off >>= 1) {
        local += __shfl_down(local, off);
        lin   += __shfl_down(lin, off);
    }
    __shared__ float s_local[2], s_lin[2];
    const int wave = threadIdx.x >> 6;
    if ((threadIdx.x & 63) == 0) { s_local[wave] = local; s_lin[wave] = lin; }
    __syncthreads();
    if (threadIdx.x == 0) {
        const float inter  = 0.5f * (s_local[0] + s_local[1]);
        const float linear = s_lin[0] + s_lin[1];
        out[row] = w0[0] + linear + inter;
    }
}

extern "C" void kernel_launch(void* const* d_in, const int* in_sizes, int n_in,
                              void* d_out, int out_size, void* d_ws, size_t ws_size,
                              hipStream_t stream) {
    // setup_inputs order: vals, row_idx, col_idx, batch(scalar), w0, w, v
    const float* vals    = (const float*)d_in[0];
    const int*   row_idx = (const int*)  d_in[1];
    const int*   col_idx = (const int*)  d_in[2];
    const float* w0      = (const float*)d_in[4];
    const float* w       = (const float*)d_in[5];
    const float* v       = (const float*)d_in[6];
    float*       out     = (float*)d_out;

    fm_fwd_kernel<<<FM_BATCH, FM_K, 0, stream>>>(vals, row_idx, col_idx, w0, w, v, out);
}

// Round 3
// 170.414 us; speedup vs baseline: 1.1196x; 1.1196x over previous
//
#include <hip/hip_runtime.h>

#define FM_NNZ   819200
#define FM_BATCH 16384
#define FM_K     128
#define WAVES    4          // rows per block (1 wave per row)
#define BATCH8   8          // gathers kept in flight per wave

__global__ __launch_bounds__(256) void fm_fwd_kernel(
    const float* __restrict__ vals,
    const int*   __restrict__ row_idx,
    const int*   __restrict__ col_idx,
    const float* __restrict__ w0,
    const float* __restrict__ w,
    const float* __restrict__ v,
    float*       __restrict__ out)
{
    const int wave = threadIdx.x >> 6;
    const int lane = threadIdx.x & 63;
    const int row  = blockIdx.x * WAVES + wave;

    // --- binary search row segment [start, end) in sorted row_idx (uniform per wave) ---
    int lo = 0, hi = FM_NNZ;
    while (lo < hi) {
        int mid = (lo + hi) >> 1;
        if (row_idx[mid] < row) lo = mid + 1; else hi = mid;
    }
    const int start = lo;
    hi = FM_NNZ;
    while (lo < hi) {
        int mid = (lo + hi) >> 1;
        if (row_idx[mid] < row + 1) lo = mid + 1; else hi = mid;
    }
    const int end = lo;

    const float2* __restrict__ v2 = (const float2*)v;   // row stride = 64 float2

    float2 xv = make_float2(0.f, 0.f);   // sum val * v[col, 2*lane(+1)]
    float2 sq = make_float2(0.f, 0.f);   // sum val * v^2
    float  lin = 0.f;

    for (int base = start; base < end; base += 64) {
        const int cnt = min(64, end - base);

        // coalesced, unconditional chunk load: lane i owns nnz (base+i)
        const int idxc = min(base + lane, FM_NNZ - 1);
        const int   c  = col_idx[idxc];
        const float a  = (lane < cnt) ? vals[idxc] : 0.f;

        // linear term: lane-parallel gather of w (a==0 kills padding)
        lin = fmaf(a, w[c], lin);

        // interaction: broadcast each nnz via shfl (register→register, no mem dep)
        int j = 0;
        for (; j + BATCH8 <= cnt; j += BATCH8) {
            float2 vv[BATCH8];
            float  aa[BATCH8];
            #pragma unroll
            for (int u = 0; u < BATCH8; ++u) {
                const int   cj = __shfl(c, j + u);
                aa[u] = __shfl(a, j + u);
                vv[u] = v2[(size_t)cj * 64 + lane];   // 512B/wave gather, independent
            }
            #pragma unroll
            for (int u = 0; u < BATCH8; ++u) {
                const float tx = aa[u] * vv[u].x;
                const float ty = aa[u] * vv[u].y;
                xv.x += tx;  xv.y += ty;
                sq.x = fmaf(tx, vv[u].x, sq.x);
                sq.y = fmaf(ty, vv[u].y, sq.y);
            }
        }
        for (; j < cnt; ++j) {
            const int   cj = __shfl(c, j);
            const float aj = __shfl(a, j);
            const float2 vvj = v2[(size_t)cj * 64 + lane];
            const float tx = aj * vvj.x;
            const float ty = aj * vvj.y;
            xv.x += tx;  xv.y += ty;
            sq.x = fmaf(tx, vvj.x, sq.x);
            sq.y = fmaf(ty, vvj.y, sq.y);
        }
    }

    // --- per-lane partial of (sum xv^2 - sum sq), then wave reduction ---
    float part = xv.x * xv.x + xv.y * xv.y - sq.x - sq.y;
    #pragma unroll
    for (int off = 32; off > 0; off >>= 1) {
        part += __shfl_down(part, off);
        lin  += __shfl_down(lin,  off);
    }
    if (lane == 0) {
        out[row] = w0[0] + lin + 0.5f * part;
    }
}

extern "C" void kernel_launch(void* const* d_in, const int* in_sizes, int n_in,
                              void* d_out, int out_size, void* d_ws, size_t ws_size,
                              hipStream_t stream) {
    // setup_inputs order: vals, row_idx, col_idx, batch(scalar), w0, w, v
    const float* vals    = (const float*)d_in[0];
    const int*   row_idx = (const int*)  d_in[1];
    const int*   col_idx = (const int*)  d_in[2];
    const float* w0      = (const float*)d_in[4];
    const float* w       = (const float*)d_in[5];
    const float* v       = (const float*)d_in[6];
    float*       out     = (float*)d_out;

    fm_fwd_kernel<<<FM_BATCH / WAVES, 64 * WAVES, 0, stream>>>(
        vals, row_idx, col_idx, w0, w, v, out);
}